// Round 1
// baseline (745.266 us; speedup 1.0000x reference)
//
#include <hip/hip_runtime.h>
#include <hip/hip_bf16.h>

#define B_N 8192
#define K_N 16
#define D_N 1024
#define C_N 512
#define BM  32

typedef __bf16 bf16x8 __attribute__((ext_vector_type(8)));
typedef float  f32x4  __attribute__((ext_vector_type(4)));
typedef float  f32x4v __attribute__((ext_vector_type(4)));
typedef unsigned int u32x4 __attribute__((ext_vector_type(4)));
typedef unsigned int u32x2 __attribute__((ext_vector_type(2)));

static __device__ __forceinline__ unsigned short f2bf(float f) {
    union { float f; unsigned int u; } x; x.f = f;
    unsigned int r = x.u + 0x7FFFu + ((x.u >> 16) & 1u);   // RNE
    return (unsigned short)(r >> 16);
}

static __device__ __forceinline__ bf16x8 load_bf8(const unsigned short* p) {
    union { u32x4 u; bf16x8 v; } t;
    t.u = *(const u32x4*)p;
    return t.v;
}

static __device__ __forceinline__ bf16x8 zero_bf8() {
    union { u32x4 u; bf16x8 v; } t;
    u32x4 z = {0u, 0u, 0u, 0u};
    t.u = z;
    return t.v;
}

// ---------------- setup kernels ----------------

__global__ void initk(int* counts, int* cursors, float* ce_sums) {
    int t = threadIdx.x;
    if (t < K_N) { counts[t] = 0; cursors[t] = 0; ce_sums[t] = 0.f; }
}

__global__ void countk(const int* __restrict__ slot_ids, int* __restrict__ counts) {
    __shared__ int h[K_N];
    if (threadIdx.x < K_N) h[threadIdx.x] = 0;
    __syncthreads();
    for (int b = blockIdx.x * blockDim.x + threadIdx.x; b < B_N; b += gridDim.x * blockDim.x)
        atomicAdd(&h[slot_ids[b]], 1);
    __syncthreads();
    if (threadIdx.x < K_N) atomicAdd(&counts[threadIdx.x], h[threadIdx.x]);
}

__global__ void scank(const int* __restrict__ counts, int* __restrict__ offsets) {
    if (threadIdx.x == 0 && blockIdx.x == 0) {
        int a = 0;
        for (int s = 0; s < K_N; ++s) { offsets[s] = a; a += counts[s]; }
    }
}

__global__ void scatterk(const int* __restrict__ slot_ids, const int* __restrict__ labels,
                         const int* __restrict__ offsets, int* __restrict__ cursors,
                         int* __restrict__ order_rows, int* __restrict__ lab_g) {
    for (int b = blockIdx.x * blockDim.x + threadIdx.x; b < B_N; b += gridDim.x * blockDim.x) {
        int s = slot_ids[b];
        int p = atomicAdd(&cursors[s], 1);
        int idx = offsets[s] + p;
        order_rows[idx] = b * K_N + s;   // flat row into concepts (b,s,:)
        lab_g[idx] = labels[b];
    }
}

// W fp32 (K,C,D) -> bf16
__global__ void convw(const float* __restrict__ W, unsigned short* __restrict__ Wb) {
    int i = (blockIdx.x * 256 + threadIdx.x) * 8;
    f32x4v a = *(const f32x4v*)(W + i);
    f32x4v b = *(const f32x4v*)(W + i + 4);
    u32x4 o;
    o[0] = (unsigned)f2bf(a[0]) | ((unsigned)f2bf(a[1]) << 16);
    o[1] = (unsigned)f2bf(a[2]) | ((unsigned)f2bf(a[3]) << 16);
    o[2] = (unsigned)f2bf(b[0]) | ((unsigned)f2bf(b[1]) << 16);
    o[3] = (unsigned)f2bf(b[2]) | ((unsigned)f2bf(b[3]) << 16);
    *(u32x4*)(Wb + i) = o;
}

// gather selected concept rows into bucketed order, fp32 -> bf16
__global__ void gatherx(const float* __restrict__ concepts, const int* __restrict__ order_rows,
                        unsigned short* __restrict__ Xg) {
    int idx = blockIdx.x;
    int row = order_rows[idx];
    const float* in = concepts + (size_t)row * D_N;
    unsigned short* out = Xg + (size_t)idx * D_N;
    int t = threadIdx.x * 4;
    f32x4v a = *(const f32x4v*)(in + t);
    u32x2 o;
    o[0] = (unsigned)f2bf(a[0]) | ((unsigned)f2bf(a[1]) << 16);
    o[1] = (unsigned)f2bf(a[2]) | ((unsigned)f2bf(a[3]) << 16);
    *(u32x2*)(out + t) = o;
}

// ---------------- GEMM + fused CE ----------------
// block: BM=32 rows x all 512 classes. 4 waves, each 128 classes (8 n-tiles of 16).
__global__ __launch_bounds__(256) void gemm_ce(
        const unsigned short* __restrict__ Xg, const unsigned short* __restrict__ Wb,
        const float* __restrict__ bias, const int* __restrict__ counts,
        const int* __restrict__ offsets, const int* __restrict__ lab_g,
        float* __restrict__ ce_sums) {
    int s = blockIdx.y;
    int cnt = counts[s];
    int row0 = blockIdx.x * BM;
    if (row0 >= cnt) return;
    int nrows = min(BM, cnt - row0);
    int base = offsets[s];

    int tid = threadIdx.x;
    int wave = tid >> 6, lane = tid & 63;
    int col = lane & 15, quad = lane >> 4;
    int c0 = wave * 128;

    f32x4 acc[2][8];
    f32x4 zf = {0.f, 0.f, 0.f, 0.f};
#pragma unroll
    for (int m = 0; m < 2; ++m)
#pragma unroll
        for (int t = 0; t < 8; ++t) acc[m][t] = zf;

    // A row pointers (clamped for safety; frags zeroed when invalid)
    const unsigned short* aptr[2];
    bool avalid[2];
#pragma unroll
    for (int m = 0; m < 2; ++m) {
        int lr = m * 16 + col;
        avalid[m] = lr < nrows;
        int gr = base + row0 + (avalid[m] ? lr : 0);
        aptr[m] = Xg + (size_t)gr * D_N + quad * 8;
    }
    const unsigned short* bptr = Wb + ((size_t)s * C_N + c0 + col) * D_N + quad * 8;

    for (int k = 0; k < D_N; k += 32) {
        bf16x8 af[2];
#pragma unroll
        for (int m = 0; m < 2; ++m)
            af[m] = avalid[m] ? load_bf8(aptr[m] + k) : zero_bf8();
        bf16x8 bfr[8];
#pragma unroll
        for (int t = 0; t < 8; ++t)
            bfr[t] = load_bf8(bptr + (size_t)t * 16 * D_N + k);
#pragma unroll
        for (int m = 0; m < 2; ++m)
#pragma unroll
            for (int t = 0; t < 8; ++t)
                acc[m][t] = __builtin_amdgcn_mfma_f32_16x16x32_bf16(af[m], bfr[t], acc[m][t], 0, 0, 0);
    }

    // epilogue: bias + per-row logsumexp + label logit + CE
    __shared__ float smax[4][BM];
    __shared__ float ssum[4][BM];
    __shared__ float gmax[BM];
    __shared__ float slab[BM];

#pragma unroll
    for (int t = 0; t < 8; ++t) {
        float bv = bias[(size_t)s * C_N + c0 + t * 16 + col];
#pragma unroll
        for (int m = 0; m < 2; ++m)
#pragma unroll
            for (int r = 0; r < 4; ++r) acc[m][t][r] += bv;
    }

    // per-wave row max over its 128 classes
#pragma unroll
    for (int m = 0; m < 2; ++m)
#pragma unroll
        for (int r = 0; r < 4; ++r) {
            float v = acc[m][0][r];
#pragma unroll
            for (int t = 1; t < 8; ++t) v = fmaxf(v, acc[m][t][r]);
            v = fmaxf(v, __shfl_xor(v, 1, 64));
            v = fmaxf(v, __shfl_xor(v, 2, 64));
            v = fmaxf(v, __shfl_xor(v, 4, 64));
            v = fmaxf(v, __shfl_xor(v, 8, 64));
            if (col == 0) smax[wave][m * 16 + quad * 4 + r] = v;
        }
    __syncthreads();
    if (tid < BM)
        gmax[tid] = fmaxf(fmaxf(smax[0][tid], smax[1][tid]),
                          fmaxf(smax[2][tid], smax[3][tid]));
    __syncthreads();

    // per-wave sum(exp) + label-logit capture
#pragma unroll
    for (int m = 0; m < 2; ++m)
#pragma unroll
        for (int r = 0; r < 4; ++r) {
            int row = m * 16 + quad * 4 + r;
            float gm = gmax[row];
            int lab = (row < nrows) ? lab_g[base + row0 + row] : -1;
            float sv = 0.f;
#pragma unroll
            for (int t = 0; t < 8; ++t) {
                float x = acc[m][t][r];
                sv += __expf(x - gm);
                if (c0 + t * 16 + col == lab) slab[row] = x;
            }
            sv += __shfl_xor(sv, 1, 64);
            sv += __shfl_xor(sv, 2, 64);
            sv += __shfl_xor(sv, 4, 64);
            sv += __shfl_xor(sv, 8, 64);
            if (col == 0) ssum[wave][row] = sv;
        }
    __syncthreads();

    if (wave == 0) {
        float ce = 0.f;
        if (lane < nrows) {
            float gs = ssum[0][lane] + ssum[1][lane] + ssum[2][lane] + ssum[3][lane];
            ce = gmax[lane] + __logf(gs) - slab[lane];
        }
        ce += __shfl_xor(ce, 1, 64);
        ce += __shfl_xor(ce, 2, 64);
        ce += __shfl_xor(ce, 4, 64);
        ce += __shfl_xor(ce, 8, 64);
        ce += __shfl_xor(ce, 16, 64);
        ce += __shfl_xor(ce, 32, 64);
        if (lane == 0) atomicAdd(&ce_sums[s], ce);
    }
}

__global__ void finalize(const int* __restrict__ counts, const float* __restrict__ ce_sums,
                         float* __restrict__ out) {
    if (threadIdx.x == 0 && blockIdx.x == 0) {
        float tot = 0.f; int np = 0;
        for (int s = 0; s < K_N; ++s) {
            int c = counts[s];
            if (c > 0) { tot += ce_sums[s] / (float)c; np++; }
        }
        out[0] = tot / (float)(np > 0 ? np : 1);
    }
}

extern "C" void kernel_launch(void* const* d_in, const int* in_sizes, int n_in,
                              void* d_out, int out_size, void* d_ws, size_t ws_size,
                              hipStream_t stream) {
    const float* concepts = (const float*)d_in[0];
    const int*   slot_ids = (const int*)d_in[1];
    const int*   labels   = (const int*)d_in[2];
    const float* W        = (const float*)d_in[3];
    const float* bias     = (const float*)d_in[4];
    float* out = (float*)d_out;

    char* ws = (char*)d_ws;
    int*   counts     = (int*)(ws + 0);
    int*   offsets    = (int*)(ws + 64);
    int*   cursors    = (int*)(ws + 128);
    float* ce_sums    = (float*)(ws + 192);
    int*   order_rows = (int*)(ws + 256);
    int*   lab_g      = (int*)(ws + 256 + 4 * B_N);
    unsigned short* Wb = (unsigned short*)(ws + 131072);
    unsigned short* Xg = (unsigned short*)(ws + 131072 + (size_t)2 * K_N * C_N * D_N);
    // total ws use: 131072 + 16 MiB + 16 MiB ~= 33.7 MB

    initk<<<1, 64, 0, stream>>>(counts, cursors, ce_sums);
    countk<<<32, 256, 0, stream>>>(slot_ids, counts);
    scank<<<1, 1, 0, stream>>>(counts, offsets);
    scatterk<<<32, 256, 0, stream>>>(slot_ids, labels, offsets, cursors, order_rows, lab_g);
    convw<<<(K_N * C_N * D_N) / (256 * 8), 256, 0, stream>>>(W, Wb);
    gatherx<<<B_N, 256, 0, stream>>>(concepts, order_rows, Xg);
    gemm_ce<<<dim3(B_N / BM, K_N), 256, 0, stream>>>(Xg, Wb, bias, counts, offsets, lab_g, ce_sums);
    finalize<<<1, 1, 0, stream>>>(counts, ce_sums, out);
}